// Round 1
// baseline (604.095 us; speedup 1.0000x reference)
//
#include <hip/hip_runtime.h>
#include <hip/hip_bf16.h>
#include <math.h>

typedef __attribute__((ext_vector_type(8))) short bf16x8;
typedef __attribute__((ext_vector_type(4))) float f32x4;
typedef __attribute__((ext_vector_type(4))) unsigned short u16x4;

constexpr int Bn = 64;    // dialogues
constexpr int Ln = 512;   // utterances
constexpr int Hd = 768;   // hidden
constexpr int Nn = 50;    // nodes per dialogue
constexpr int On = 768;   // output dim
constexpr int RP = 64;    // padded rows per dialogue (M = Bn*RP = 4096)

constexpr int NCNT = 5 * Bn;                  // dependency counters (ints)
constexpr int AUXW = 5 * Bn * RP + NCNT;      // zeroed 4B words in aux region

__device__ __forceinline__ f32x4 MFMA(bf16x8 a, bf16x8 b, f32x4 c) {
  return __builtin_amdgcn_mfma_f32_16x16x32_bf16(a, b, c, 0, 0, 0);
}
__device__ __forceinline__ unsigned short f2bb(float v) {
  __hip_bfloat16 h = __float2bfloat16(v);
  return *(unsigned short*)&h;
}

// ===========================================================================
// prep, one launch, job ranges by blockIdx.x:
//   [0,2304)      transpose+cvt W1,W2,Wa,Wl (f32 -> bf16^T)
//   [2304,6400)   gather+PE into padded xb (bf16) / xres (f32); pad rows = 0
//   [6400,6482)   zero aux accumulators + dependency counters
struct PrepArgs {
  const float* src[4];
  __hip_bfloat16* dst[4];
  const float* emb;
  const int* ids;
  float* xres;
  __hip_bfloat16* xb;
  float* aux;
};

__global__ __launch_bounds__(256) void prep_kernel(PrepArgs a) {
  int bx = blockIdx.x;
  if (bx < 2304) {
    __shared__ float tile[32][33];
    int job = bx / 576, t = bx % 576;
    const float* W = a.src[job];
    __hip_bfloat16* Wt = a.dst[job];
    int tx = (t % 24) * 32, ty = (t / 24) * 32;
    int c = threadIdx.x & 31, r0 = threadIdx.x >> 5;
    for (int r = r0; r < 32; r += 8)
      tile[r][c] = W[(size_t)(tx + r) * Hd + ty + c];
    __syncthreads();
    for (int r = r0; r < 32; r += 8)
      Wt[(size_t)(ty + r) * Hd + tx + c] = __float2bfloat16(tile[c][r]);
  } else if (bx < 6400) {
    int bn = bx - 2304;          // b*RP + i
    int b = bn >> 6, i = bn & 63;
    __hip_bfloat16* xbo = a.xb + (size_t)bn * Hd;
    float* xro = a.xres + (size_t)bn * Hd;
    if (i < Nn) {
      int id = a.ids[b * Nn + i];
      const float* src = a.emb + ((size_t)b * Ln + id) * Hd;
      const float kLog = 9.210340371976184f / (float)Hd;  // ln(10000)/H
      for (int h = threadIdx.x; h < Hd; h += 256) {
        float freq = expf(-(float)(h & ~1) * kLog);
        float ang = (float)i * freq;
        float v = src[h] + ((h & 1) ? cosf(ang) : sinf(ang));
        xbo[h] = __float2bfloat16(v);
        xro[h] = v;
      }
    } else {
      for (int h = threadIdx.x; h < Hd; h += 256) {
        xbo[h] = __float2bfloat16(0.f);
        xro[h] = 0.f;
      }
    }
  } else {
    int idx = (bx - 6400) * 256 + threadIdx.x;
    if (idx < AUXW) a.aux[idx] = 0.f;
  }
}

// ===========================================================================
// Device-scope dependency plumbing (per-dialogue counters).
// Release/acquire at agent scope: per-XCD L2s are not cross-coherent.
__device__ __forceinline__ void wait_cnt(const int* c, int need) {
  if (threadIdx.x == 0) {
    while (__hip_atomic_load(c, __ATOMIC_ACQUIRE, __HIP_MEMORY_SCOPE_AGENT) <
           need) {
      __builtin_amdgcn_s_sleep(2);
    }
  }
  __syncthreads();
}
__device__ __forceinline__ void signal_cnt(int* c) {
  __syncthreads();  // all waves drained their stores (vmcnt(0) before barrier)
  if (threadIdx.x == 0) {
    __threadfence();
    __hip_atomic_fetch_add(c, 1, __ATOMIC_RELEASE, __HIP_MEMORY_SCOPE_AGENT);
  }
}

// ===========================================================================
// Task bodies — copied verbatim from the proven standalone kernels, with
// blockIdx replaced by (b, col0/cg) params and __shared__ replaced by a
// caller-provided LDS arena. Every task is entered/exited via a
// __syncthreads() (inside wait_cnt/signal_cnt), so LDS reuse is race-free.

// Per-dialogue GEMM tile: C = A[b*64..+64, :] @ Wt^T + bias, 64x64 cols.
// EPI 0: write Wh^T + fused src/dst dots. EPI 1: tanh(C+bias).v into o1.
template <int EPI>
__device__ void gemm_task(char* smemraw, int b, int col0,
                          const __hip_bfloat16* __restrict__ A,
                          const __hip_bfloat16* __restrict__ Bt,
                          const float* __restrict__ bias,
                          __hip_bfloat16* __restrict__ WhT,
                          const float* __restrict__ avec,
                          float* __restrict__ o1, float* __restrict__ o2) {
  typedef __hip_bfloat16 Tile[64][40];
  Tile* As = reinterpret_cast<Tile*>(smemraw);            // [2][64][40]
  Tile* Bs = reinterpret_cast<Tile*>(smemraw + 10240);    // [2][64][40]
  int tid = threadIdx.x;
  int wave = tid >> 6, lane = tid & 63;
  int lr = lane & 15, lq = lane >> 4;
  int row0 = b * RP;
  int sr = tid >> 2, sk = (tid & 3) * 8;
  const __hip_bfloat16* Ap = A + (size_t)(row0 + sr) * Hd + sk;
  const __hip_bfloat16* Bp = Bt + (size_t)(col0 + sr) * Hd + sk;
  uint4 ra = *(const uint4*)Ap;
  uint4 rb = *(const uint4*)Bp;
  *(uint4*)&As[0][sr][sk] = ra;
  *(uint4*)&Bs[0][sr][sk] = rb;
  f32x4 acc[4] = {};
  __syncthreads();
  int cur = 0;
  for (int kt = 32; kt < Hd; kt += 32) {
    ra = *(const uint4*)(Ap + kt);
    rb = *(const uint4*)(Bp + kt);
    bf16x8 af = *(const bf16x8*)&As[cur][wave * 16 + lr][lq * 8];
#pragma unroll
    for (int ct = 0; ct < 4; ++ct)
      acc[ct] = MFMA(af, *(const bf16x8*)&Bs[cur][ct * 16 + lr][lq * 8], acc[ct]);
    *(uint4*)&As[cur ^ 1][sr][sk] = ra;
    *(uint4*)&Bs[cur ^ 1][sr][sk] = rb;
    __syncthreads();
    cur ^= 1;
  }
  {
    bf16x8 af = *(const bf16x8*)&As[cur][wave * 16 + lr][lq * 8];
#pragma unroll
    for (int ct = 0; ct < 4; ++ct)
      acc[ct] = MFMA(af, *(const bf16x8*)&Bs[cur][ct * 16 + lr][lq * 8], acc[ct]);
  }
  int lrow0 = wave * 16 + lq * 4;  // local row base (0..60, mult of 4)
  if (EPI == 0) {
    float ps[4] = {}, pd[4] = {};
#pragma unroll
    for (int ct = 0; ct < 4; ++ct) {
      int gc = col0 + ct * 16 + lr;
      float bv = bias[gc];
      float a_s = avec[gc], a_d = avec[Hd + gc];
      u16x4 pk;
#pragma unroll
      for (int r = 0; r < 4; ++r) {
        float v = acc[ct][r] + bv;
        pk[r] = f2bb(v);
        ps[r] += v * a_s;
        pd[r] += v * a_d;
      }
      *(u16x4*)(WhT + ((size_t)b * Hd + gc) * RP + lrow0) = pk;
    }
#pragma unroll
    for (int off = 8; off; off >>= 1)
#pragma unroll
      for (int r = 0; r < 4; ++r) {
        ps[r] += __shfl_xor(ps[r], off);
        pd[r] += __shfl_xor(pd[r], off);
      }
    if (lr == 0)
#pragma unroll
      for (int r = 0; r < 4; ++r) {
        int row = lrow0 + r;
        if (row < Nn) {
          atomicAdd(&o1[b * RP + row], ps[r]);
          atomicAdd(&o2[b * RP + row], pd[r]);
        }
      }
  } else {
    float pr[4] = {};
#pragma unroll
    for (int ct = 0; ct < 4; ++ct) {
      int gc = col0 + ct * 16 + lr;
      float bv = bias[gc];
      float vv_ = avec[gc];
#pragma unroll
      for (int r = 0; r < 4; ++r) pr[r] += tanhf(acc[ct][r] + bv) * vv_;
    }
#pragma unroll
    for (int off = 8; off; off >>= 1)
#pragma unroll
      for (int r = 0; r < 4; ++r) pr[r] += __shfl_xor(pr[r], off);
    if (lr == 0)
#pragma unroll
      for (int r = 0; r < 4; ++r) {
        int row = lrow0 + r;
        if (row < Nn) atomicAdd(&o1[b * RP + row], pr[r]);
      }
  }
}

// MFMA attention apply for one (dialogue b, col-group cg of 256 cols).
template <int LAYER>
__device__ void attf_task(char* smemraw, int b, int cg,
                          const float* __restrict__ ssrc,
                          const float* __restrict__ sdst,
                          const int* __restrict__ adj,
                          const float* __restrict__ ab,
                          const __hip_bfloat16* __restrict__ WhT,
                          const float* __restrict__ xres,
                          float* __restrict__ hf,
                          __hip_bfloat16* __restrict__ hb) {
  float* attL = reinterpret_cast<float*>(smemraw);                     // Nn*52
  __hip_bfloat16* attB =
      reinterpret_cast<__hip_bfloat16*>(smemraw + Nn * 52 * 4);        // 64*72
  int tid = threadIdx.x;
  float abv = ab[0];
  for (int i = tid; i < 64 * 72; i += 256) attB[i] = __float2bfloat16(0.f);
  for (int idx = tid; idx < Nn * Nn; idx += 256) {
    int i = idx / Nn, j = idx - i * Nn;
    float t = ssrc[b * RP + i] + sdst[b * RP + j] + abv;
    t = t > 0.f ? t : 0.3f * t;  // leaky_relu 0.3
    attL[i * 52 + j] = (adj[(size_t)b * Nn * Nn + idx] > 0) ? t : -9.0e15f;
  }
  __syncthreads();
  if (tid < Nn) {
    float m = -3.0e38f;
    for (int j = 0; j < Nn; ++j) m = fmaxf(m, attL[tid * 52 + j]);
    float s = 0.f;
    for (int j = 0; j < Nn; ++j) {
      float p = expf(attL[tid * 52 + j] - m);
      attL[tid * 52 + j] = p;
      s += p;
    }
    float inv = 1.f / s;
    for (int j = 0; j < Nn; ++j) attL[tid * 52 + j] *= inv;
  }
  __syncthreads();
  for (int idx = tid; idx < Nn * Nn; idx += 256) {
    int i = idx / Nn, j = idx - i * Nn;
    attB[i * 72 + j] = __float2bfloat16(attL[i * 52 + j]);
  }
  __syncthreads();

  int w = tid >> 6, lane = tid & 63, lr = lane & 15, lq = lane >> 4;
  bf16x8 a0 = *(const bf16x8*)&attB[(w * 16 + lr) * 72 + lq * 8];
  bf16x8 a1 = *(const bf16x8*)&attB[(w * 16 + lr) * 72 + 32 + lq * 8];
#pragma unroll
  for (int s = 0; s < 16; ++s) {
    int gc = cg * 256 + s * 16 + lr;
    const __hip_bfloat16* Bp = WhT + ((size_t)b * Hd + gc) * RP + lq * 8;
    f32x4 acc = {};
    acc = MFMA(a0, *(const bf16x8*)Bp, acc);
    acc = MFMA(a1, *(const bf16x8*)(Bp + 32), acc);
#pragma unroll
    for (int r = 0; r < 4; ++r) {
      float v = acc[r];
      v = v > 0.f ? v : expf(v) - 1.f;  // elu
      size_t off = ((size_t)b * RP + w * 16 + lq * 4 + r) * Hd + gc;
      if (LAYER == 2) {
        v += xres[off];
        hf[off] = v;
      }
      hb[off] = __float2bfloat16(v);
    }
  }
}

// Pool softmax + weighted sum + final linear for one dialogue.
__device__ void pool_task(char* smemraw, int b, const float* __restrict__ sraw,
                          const float* __restrict__ h2,
                          const __hip_bfloat16* __restrict__ Wlt,
                          const float* __restrict__ bl,
                          float* __restrict__ out) {
  float* sc = reinterpret_cast<float*>(smemraw);         // Nn floats
  float* ds = reinterpret_cast<float*>(smemraw + 256);   // Hd floats
  if (threadIdx.x < 64) {
    int j = threadIdx.x;
    float e = (j < Nn) ? sraw[b * RP + j] : -3.0e38f;
    float m = e;
#pragma unroll
    for (int off = 32; off; off >>= 1) m = fmaxf(m, __shfl_xor(m, off));
    float p = (j < Nn) ? expf(e - m) : 0.f;
    float s = p;
#pragma unroll
    for (int off = 32; off; off >>= 1) s += __shfl_xor(s, off);
    if (j < Nn) sc[j] = p / s;
  }
  __syncthreads();
  for (int h = threadIdx.x; h < Hd; h += 256) {
    float a = 0.f;
#pragma unroll 10
    for (int j = 0; j < Nn; ++j) a += sc[j] * h2[((size_t)b * RP + j) * Hd + h];
    ds[h] = a;
  }
  __syncthreads();
  for (int oo = 0; oo < 3; ++oo) {
    int o = oo * 256 + threadIdx.x;
    float acc = bl[o];
    const uint4* wr = (const uint4*)(Wlt + (size_t)o * Hd);
    for (int kk = 0; kk < Hd / 8; ++kk) {
      union { uint4 u; unsigned short s[8]; } w;
      w.u = wr[kk];
#pragma unroll
      for (int t = 0; t < 8; ++t)
        acc += ds[kk * 8 + t] * __uint_as_float((unsigned)w.s[t] << 16);
    }
    out[(size_t)b * On + o] = acc;
  }
}

// ===========================================================================
// Persistent pipeline kernel. grid = 512 blocks x 256 threads.
// Co-residency: __launch_bounds__(256,2) caps VGPR<=256 => >=2 blocks/CU
// (LDS 20.5KB is no constraint), so all 512 blocks are resident and the
// stage-ordered per-block task lists guarantee forward progress (all stage-k
// tasks precede every stage-(k+1) wait in every block's program order).
//
// Task map (dialogue b, 64 dialogues):
//   G1: 768 tasks (b,cg12)  -> block g takes t = g, g+512
//   A1: 192 tasks (b,cg3)   -> block 256+t          (needs cnt1[b]==12)
//   G2: 768 tasks           -> t = g, g+512         (needs cnt2[b]==3)
//   A2: 192 tasks           -> block 511-t          (needs cnt3[b]==12)
//   G3: 768 tasks           -> t = g, g+512         (needs cnt4[b]==3)
//   P : 64 tasks            -> block 448+b          (needs cnt5[b]==12)
struct MegaArgs {
  const __hip_bfloat16 *xb, *Wt1, *Wt2, *Wta, *Wlt;
  const float *xres;
  const float *b1, *a1, *ab1, *b2, *a2, *ab2, *ba, *vv, *bl;
  const int* adj;
  float *ssrc1, *sdst1, *ssrc2, *sdst2, *sraw;
  __hip_bfloat16 *WhT1, *WhT2, *h1b, *h2b;
  float *h2f;
  float* out;
  int* cnt;  // [5][Bn]
};

__global__ __launch_bounds__(256, 2) void mega_kernel(MegaArgs m) {
  __shared__ __align__(16) char smem[20608];
  int g = blockIdx.x;
  int* c1 = m.cnt;
  int* c2 = c1 + Bn;
  int* c3 = c2 + Bn;
  int* c4 = c3 + Bn;
  int* c5 = c4 + Bn;

  // --- stage G1: xb @ W1 (+ssrc1/sdst1 epilogue) ---
  for (int t = g; t < 768; t += 512) {
    int b = t / 12;
    gemm_task<0>(smem, b, (t % 12) * 64, m.xb, m.Wt1, m.b1, m.WhT1, m.a1,
                 m.ssrc1, m.sdst1);
    signal_cnt(&c1[b]);
  }
  // --- stage A1: attention apply, layer 1 ---
  if (g >= 256 && g < 448) {
    int t = g - 256, b = t / 3;
    wait_cnt(&c1[b], 12);
    attf_task<1>(smem, b, t % 3, m.ssrc1, m.sdst1, m.adj, m.ab1, m.WhT1,
                 nullptr, nullptr, m.h1b);
    signal_cnt(&c2[b]);
  }
  // --- stage G2: h1 @ W2 ---
  for (int t = g; t < 768; t += 512) {
    int b = t / 12;
    wait_cnt(&c2[b], 3);
    gemm_task<0>(smem, b, (t % 12) * 64, m.h1b, m.Wt2, m.b2, m.WhT2, m.a2,
                 m.ssrc2, m.sdst2);
    signal_cnt(&c3[b]);
  }
  // --- stage A2: attention apply, layer 2 (+residual) ---
  if (g >= 320) {
    int t = 511 - g, b = t / 3;
    wait_cnt(&c3[b], 12);
    attf_task<2>(smem, b, t % 3, m.ssrc2, m.sdst2, m.adj, m.ab2, m.WhT2,
                 m.xres, m.h2f, m.h2b);
    signal_cnt(&c4[b]);
  }
  // --- stage G3: pooling scores sraw = tanh(h2 @ Wa + ba) . v ---
  for (int t = g; t < 768; t += 512) {
    int b = t / 12;
    wait_cnt(&c4[b], 3);
    gemm_task<1>(smem, b, (t % 12) * 64, m.h2b, m.Wta, m.ba, nullptr, m.vv,
                 m.sraw, nullptr);
    signal_cnt(&c5[b]);
  }
  // --- stage P: pool + final linear ---
  if (g >= 448) {
    int b = g - 448;
    wait_cnt(&c5[b], 12);
    pool_task(smem, b, m.sraw, m.h2f, m.Wlt, m.bl, m.out);
  }
}

// ===========================================================================
extern "C" void kernel_launch(void* const* d_in, const int* in_sizes, int n_in,
                              void* d_out, int out_size, void* d_ws, size_t ws_size,
                              hipStream_t stream) {
  const float* emb = (const float*)d_in[0];
  const int* ids = (const int*)d_in[1];
  const int* adj = (const int*)d_in[2];
  const float* W1 = (const float*)d_in[3];
  const float* b1 = (const float*)d_in[4];
  const float* a1 = (const float*)d_in[5];
  const float* ab1 = (const float*)d_in[6];
  const float* W2 = (const float*)d_in[7];
  const float* b2 = (const float*)d_in[8];
  const float* a2 = (const float*)d_in[9];
  const float* ab2 = (const float*)d_in[10];
  const float* Wa = (const float*)d_in[11];
  const float* ba = (const float*)d_in[12];
  const float* vv = (const float*)d_in[13];
  const float* Wl = (const float*)d_in[14];
  const float* bl = (const float*)d_in[15];
  float* out = (float*)d_out;

  char* p = (char*)d_ws;
  auto alloc = [&](size_t bytes) {
    char* r = p;
    p += (bytes + 255) & ~(size_t)255;
    return r;
  };
  __hip_bfloat16* Wt1 = (__hip_bfloat16*)alloc((size_t)Hd * Hd * 2);
  __hip_bfloat16* Wt2 = (__hip_bfloat16*)alloc((size_t)Hd * Hd * 2);
  __hip_bfloat16* Wta = (__hip_bfloat16*)alloc((size_t)Hd * Hd * 2);
  __hip_bfloat16* Wlt = (__hip_bfloat16*)alloc((size_t)Hd * On * 2);
  float* aux = (float*)alloc((size_t)AUXW * 4);
  float* ssrc1 = aux;
  float* sdst1 = aux + Bn * RP;
  float* ssrc2 = aux + 2 * Bn * RP;
  float* sdst2 = aux + 3 * Bn * RP;
  float* sraw = aux + 4 * Bn * RP;
  int* cnt = (int*)(aux + 5 * Bn * RP);
  __hip_bfloat16* xb = (__hip_bfloat16*)alloc((size_t)Bn * RP * Hd * 2);
  float* xres = (float*)alloc((size_t)Bn * RP * Hd * 4);
  __hip_bfloat16* WhT1 = (__hip_bfloat16*)alloc((size_t)Bn * Hd * RP * 2);
  __hip_bfloat16* WhT2 = (__hip_bfloat16*)alloc((size_t)Bn * Hd * RP * 2);
  __hip_bfloat16* h1b = (__hip_bfloat16*)alloc((size_t)Bn * RP * Hd * 2);
  __hip_bfloat16* h2b = (__hip_bfloat16*)alloc((size_t)Bn * RP * Hd * 2);
  float* h2f = (float*)alloc((size_t)Bn * RP * Hd * 4);

  PrepArgs pa;
  pa.src[0] = W1; pa.src[1] = W2; pa.src[2] = Wa; pa.src[3] = Wl;
  pa.dst[0] = Wt1; pa.dst[1] = Wt2; pa.dst[2] = Wta; pa.dst[3] = Wlt;
  pa.emb = emb; pa.ids = ids; pa.xres = xres; pa.xb = xb; pa.aux = aux;
  prep_kernel<<<6482, 256, 0, stream>>>(pa);

  MegaArgs ma;
  ma.xb = xb; ma.Wt1 = Wt1; ma.Wt2 = Wt2; ma.Wta = Wta; ma.Wlt = Wlt;
  ma.xres = xres;
  ma.b1 = b1; ma.a1 = a1; ma.ab1 = ab1;
  ma.b2 = b2; ma.a2 = a2; ma.ab2 = ab2;
  ma.ba = ba; ma.vv = vv; ma.bl = bl;
  ma.adj = adj;
  ma.ssrc1 = ssrc1; ma.sdst1 = sdst1; ma.ssrc2 = ssrc2; ma.sdst2 = sdst2;
  ma.sraw = sraw;
  ma.WhT1 = WhT1; ma.WhT2 = WhT2; ma.h1b = h1b; ma.h2b = h2b;
  ma.h2f = h2f; ma.out = out; ma.cnt = cnt;
  mega_kernel<<<512, 256, 0, stream>>>(ma);
}